// Round 1
// baseline (378.619 us; speedup 1.0000x reference)
//
#include <hip/hip_runtime.h>
#include <cstdio>
#include <cstdint>

#define HH 512
#define WW 512
#define CC 32
#define BB 2
#define NN 120000
#define HWPIX (HH*WW)

// INDEX_SHIFT rows (dy, dx)
__device__ const int d_dy[9] = {0,-1,1,0,-1,1,0,-1,-1+0, };
__device__ const int d_dy_real[9] = {0,-1,1,0,-1,1,0,-1,1};
__device__ const int d_dx_real[9] = {0,0,0,1,1,1,-1,-1,-1};

// ---------------- compose fused weight matrices ----------------
// M layout (floats): [0:1024) MqT, [1024:2048) MkT, [2048:3072) MvT, [3072:4096) owT
// MxT[j*32+c'] = (W_proj @ w_x)[c'][j];  owT[j*32+c'] = out_w[c'][j]
__global__ void compose_mats(const float* __restrict__ wq, const float* __restrict__ wk,
                             const float* __restrict__ wv, const float* __restrict__ in_w,
                             const float* __restrict__ out_w, float* __restrict__ M) {
    int tid = blockIdx.x * blockDim.x + threadIdx.x;   // 0..4095
    if (tid >= 4096) return;
    int which = tid >> 10;
    int e = tid & 1023;
    int cp = e & 31;   // output channel c'
    int j  = e >> 5;   // inner (lane-broadcast) index
    if (which < 3) {
        const float* w = (which == 0) ? wq : ((which == 1) ? wk : wv);
        const float* Wrow = in_w + (which * 32 + cp) * 32;
        float acc = 0.f;
        #pragma unroll
        for (int t = 0; t < 32; ++t) acc += Wrow[t] * w[t * 32 + j];
        M[which * 1024 + j * 32 + cp] = acc;
    } else {
        M[3 * 1024 + j * 32 + cp] = out_w[cp * 32 + j];
    }
}

// V layout (floats): [0:32) bq' = W1@bq + in_b[:32], [32:64) bk' = W2@bk,
//                    [64:96) bv' = W3@bv, [96:96+288) posp[s][c'] = (pos[s] @ W3^T)[c']
__global__ void compose_vecs(const float* __restrict__ bq, const float* __restrict__ bk,
                             const float* __restrict__ bv, const float* __restrict__ in_w,
                             const float* __restrict__ in_b, const float* __restrict__ pos_w,
                             const float* __restrict__ pos_b, float* __restrict__ V) {
    int tid = threadIdx.x;
    if (tid < 32) {
        float a = 0.f, b = 0.f, c = 0.f;
        #pragma unroll
        for (int t = 0; t < 32; ++t) {
            a += in_w[tid * 32 + t] * bq[t];
            b += in_w[(32 + tid) * 32 + t] * bk[t];
            c += in_w[(64 + tid) * 32 + t] * bv[t];
        }
        V[tid]      = a + in_b[tid];
        V[32 + tid] = b;
        V[64 + tid] = c;
    } else if (tid < 32 + 288) {
        int k = tid - 32;
        int s = k >> 5, cp = k & 31;
        float dy = (float)d_dy_real[s], dx = (float)d_dx_real[s];
        float acc = 0.f;
        #pragma unroll
        for (int t = 0; t < 32; ++t) {
            float pos_t = dy * pos_w[t * 2 + 0] + dx * pos_w[t * 2 + 1] + pos_b[t];
            acc += in_w[(64 + cp) * 32 + t] * pos_t;
        }
        V[96 + s * 32 + cp] = acc;
    }
}

// ---------------- dense coord -> point-index grid ----------------
__global__ void build_grid(const int* __restrict__ coors, int* __restrict__ grid) {
    int P = blockIdx.x * blockDim.x + threadIdx.x;
    if (P >= BB * NN) return;
    int b = P / NN;
    int n = P - b * NN;
    int y = coors[P * 2 + 0];
    int x = coors[P * 2 + 1];
    grid[b * HWPIX + y * WW + x] = n;
}

// ---------------- stage1: LayerNorm + fused q/k/v linears ----------------
// 32 lanes per point; 8 points per 256-thread block. Outputs:
//   qp[P*32+c]  (query already projected through in_w[:C])
//   kv[P*64+c] = k2, kv[P*64+32+c] = v2   (interleaved for one contiguous gather row)
__global__ __launch_bounds__(256) void stage1(const float* __restrict__ feats,
                                              const float* __restrict__ ln_w,
                                              const float* __restrict__ ln_b,
                                              const float* __restrict__ M,
                                              const float* __restrict__ V,
                                              float* __restrict__ qp,
                                              float* __restrict__ kv) {
    __shared__ float lds[3 * 1024];
    for (int i = threadIdx.x; i < 3072; i += 256) lds[i] = M[i];
    __syncthreads();

    int wid = threadIdx.x >> 5;
    int c   = threadIdx.x & 31;
    int P   = blockIdx.x * 8 + wid;           // 0..239999, grid sized exactly

    float f = feats[(size_t)P * 32 + c];
    float s1 = f, s2 = f * f;
    #pragma unroll
    for (int off = 16; off >= 1; off >>= 1) {
        s1 += __shfl_xor(s1, off, 32);
        s2 += __shfl_xor(s2, off, 32);
    }
    float mu  = s1 * (1.f / 32.f);
    float var = s2 * (1.f / 32.f) - mu * mu;
    float x = (f - mu) * rsqrtf(var + 1e-5f) * ln_w[c] + ln_b[c];

    float aq = V[c], ak = V[32 + c], av = V[64 + c];
    #pragma unroll
    for (int j = 0; j < 32; ++j) {
        float xv = __shfl(x, j, 32);
        aq += xv * lds[j * 32 + c];
        ak += xv * lds[1024 + j * 32 + c];
        av += xv * lds[2048 + j * 32 + c];
    }
    qp[(size_t)P * 32 + c]      = aq;
    kv[(size_t)P * 64 + c]      = ak;
    kv[(size_t)P * 64 + 32 + c] = av;
}

// ---------------- stage2: neighbor gather + 2-head softmax attention + out proj ----------------
// Overwrites qp[] with the final per-point output o (qp is only read by its own point).
__global__ __launch_bounds__(256) void stage2(const int* __restrict__ coors,
                                              const int* __restrict__ grid,
                                              const float* __restrict__ kv,
                                              const float* __restrict__ M,
                                              const float* __restrict__ V,
                                              const float* __restrict__ in_b,
                                              const float* __restrict__ out_b,
                                              float* __restrict__ qp) {
    __shared__ float ow[1024];
    for (int i = threadIdx.x; i < 1024; i += 256) ow[i] = M[3072 + i];
    __syncthreads();

    int wid = threadIdx.x >> 5;
    int c   = threadIdx.x & 31;
    int P   = blockIdx.x * 8 + wid;
    int b   = P / NN;

    int y  = coors[P * 2 + 0];
    int xx = coors[P * 2 + 1];
    float qv = qp[(size_t)P * 32 + c];
    float b2 = in_b[32 + c];
    float b3 = in_b[64 + c];

    float logits[9], vpr[9];
    #pragma unroll
    for (int s = 0; s < 9; ++s) {
        int sy = y + d_dy_real[s];
        int sx = xx + d_dx_real[s];
        bool valid = (sy >= 0) & (sy < HH) & (sx >= 0) & (sx < WW);
        int idx = -1;
        if (valid) idx = grid[b * HWPIX + sy * WW + sx];
        float kpc, vpc;
        if (idx >= 0) {
            size_t base = ((size_t)(b * NN + idx)) * 64;
            kpc = kv[base + c] + b2;
            vpc = kv[base + 32 + c] + V[96 + s * 32 + c] + b3;
        } else {
            kpc = b2;        // tk zeroed before projection -> only bias survives
            vpc = b3;
        }
        // head dot product: reduce within the 16-lane head group
        float d = qv * kpc;
        #pragma unroll
        for (int off = 8; off >= 1; off >>= 1) d += __shfl_xor(d, off, 16);
        logits[s] = d * 0.25f;   // 1/sqrt(HD=16)
        vpr[s] = vpc;
    }

    float m = logits[0];
    #pragma unroll
    for (int s = 1; s < 9; ++s) m = fmaxf(m, logits[s]);
    float sum = 0.f, o = 0.f;
    #pragma unroll
    for (int s = 0; s < 9; ++s) {
        float e = __expf(logits[s] - m);
        sum += e;
        o += e * vpr[s];
    }
    o /= sum;

    // output projection across all 32 channels
    float acc = out_b[c];
    #pragma unroll
    for (int j = 0; j < 32; ++j) {
        float ov = __shfl(o, j, 32);
        acc += ov * ow[j * 32 + c];
    }
    qp[(size_t)P * 32 + c] = acc;
}

// ---------------- stage3: full-canvas scatter (also zero-fills empty pixels) ----------------
__global__ __launch_bounds__(256) void stage3(const int* __restrict__ grid,
                                              const float* __restrict__ obuf,
                                              float* __restrict__ out) {
    int t = blockIdx.x * blockDim.x + threadIdx.x;   // 0 .. B*HW-1
    int b = t >> 18;                                  // HW = 2^18
    int p = t & (HWPIX - 1);
    int col = grid[t];
    float r[32];
    if (col >= 0) {
        const float4* row = (const float4*)(obuf + ((size_t)(b * NN + col)) * 32);
        #pragma unroll
        for (int i = 0; i < 8; ++i) ((float4*)r)[i] = row[i];
    } else {
        #pragma unroll
        for (int i = 0; i < 32; ++i) r[i] = 0.f;
    }
    float* outb = out + (size_t)b * CC * HWPIX + p;
    #pragma unroll
    for (int cc = 0; cc < 32; ++cc) outb[cc * HWPIX] = r[cc];
}

extern "C" void kernel_launch(void* const* d_in, const int* in_sizes, int n_in,
                              void* d_out, int out_size, void* d_ws, size_t ws_size,
                              hipStream_t stream) {
    const float* feats = (const float*)d_in[0];
    const int*   coors = (const int*)d_in[1];
    const float* ln_w  = (const float*)d_in[2];
    const float* ln_b  = (const float*)d_in[3];
    const float* wq    = (const float*)d_in[4];
    const float* bq    = (const float*)d_in[5];
    const float* wk    = (const float*)d_in[6];
    const float* bk    = (const float*)d_in[7];
    const float* wv    = (const float*)d_in[8];
    const float* bv    = (const float*)d_in[9];
    const float* pos_w = (const float*)d_in[10];
    const float* pos_b = (const float*)d_in[11];
    const float* in_w  = (const float*)d_in[12];
    const float* in_b  = (const float*)d_in[13];
    const float* out_w = (const float*)d_in[14];
    const float* out_b = (const float*)d_in[15];

    // workspace layout (floats)
    int*   grid = (int*)d_ws;
    float* qp   = (float*)d_ws + (size_t)BB * HWPIX;          // B*N*32, later reused as o
    float* kv   = qp + (size_t)BB * NN * 32;                  // B*N*64 interleaved k2|v2
    float* M    = kv + (size_t)BB * NN * 64;                  // 4096
    float* V    = M + 4096;                                   // 384

    size_t need = ((size_t)BB * HWPIX + (size_t)BB * NN * 96 + 4096 + 384) * sizeof(float);
    if (ws_size < need) {
        fprintf(stderr, "kernel_launch: ws too small: %zu < %zu\n", ws_size, need);
        return;
    }

    hipMemsetAsync(grid, 0xFF, (size_t)BB * HWPIX * sizeof(int), stream);  // grid = -1
    compose_mats<<<16, 256, 0, stream>>>(wq, wk, wv, in_w, out_w, M);
    compose_vecs<<<1, 512, 0, stream>>>(bq, bk, bv, in_w, in_b, pos_w, pos_b, V);
    build_grid<<<(BB * NN + 255) / 256, 256, 0, stream>>>(coors, grid);
    stage1<<<BB * NN / 8, 256, 0, stream>>>(feats, ln_w, ln_b, M, V, qp, kv);
    stage2<<<BB * NN / 8, 256, 0, stream>>>(coors, grid, kv, M, V, in_b, out_b, qp);
    stage3<<<BB * HWPIX / 256, 256, 0, stream>>>(grid, qp, (float*)d_out);
}

// Round 2
// 306.148 us; speedup vs baseline: 1.2367x; 1.2367x over previous
//
#include <hip/hip_runtime.h>
#include <cstdio>
#include <cstdint>

#define HH 512
#define WW 512
#define CC 32
#define BB 2
#define NN 120000
#define HWPIX (HH*WW)
#define NPTS (BB*NN)          // 240000
#define NPIX (BB*HWPIX)       // 524288
#define NBLK (NPIX/256)       // 2048

__device__ __forceinline__ float dot4(float4 a, float4 b) {
    return a.x*b.x + a.y*b.y + a.z*b.z + a.w*b.w;
}
__device__ __forceinline__ void fma4(float4& o, float w, float4 v) {
    o.x += w*v.x; o.y += w*v.y; o.z += w*v.z; o.w += w*v.w;
}
__device__ __forceinline__ float4 fin4(float4 o, float wdy, float wdx, float woc, float rl,
                                       float4 py, float4 px, float4 pb, float4 b3) {
    float4 r;
    r.x = (o.x + wdy*py.x + wdx*px.x + woc*pb.x)*rl + b3.x;
    r.y = (o.y + wdy*py.y + wdx*px.y + woc*pb.y)*rl + b3.y;
    r.z = (o.z + wdy*py.z + wdx*px.z + woc*pb.z)*rl + b3.z;
    r.w = (o.w + wdy*py.w + wdx*px.w + woc*pb.w)*rl + b3.w;
    return r;
}

// ---------------- compose fused weight matrices ----------------
// M layout (floats): [0:1024) MqT, [1024:2048) MkT, [2048:3072) MvT, [3072:4096) owT
// MxT[j*32+c'] = (W_proj @ w_x)[c'][j];  owT[j*32+c'] = out_w[c'][j]
__global__ void compose_mats(const float* __restrict__ wq, const float* __restrict__ wk,
                             const float* __restrict__ wv, const float* __restrict__ in_w,
                             const float* __restrict__ out_w, float* __restrict__ M) {
    int tid = blockIdx.x * blockDim.x + threadIdx.x;   // 0..4095
    if (tid >= 4096) return;
    int which = tid >> 10;
    int e = tid & 1023;
    int cp = e & 31;
    int j  = e >> 5;
    if (which < 3) {
        const float* w = (which == 0) ? wq : ((which == 1) ? wk : wv);
        const float* Wrow = in_w + (which * 32 + cp) * 32;
        float acc = 0.f;
        #pragma unroll
        for (int t = 0; t < 32; ++t) acc += Wrow[t] * w[t * 32 + j];
        M[which * 1024 + j * 32 + cp] = acc;
    } else {
        M[3 * 1024 + j * 32 + cp] = out_w[cp * 32 + j];
    }
}

// V layout (floats): [0:32) bq' = W1@bq + in_b[:32], [32:64) bk' = W2@bk, [64:96) bv' = W3@bv,
// [96:128) PWy[c] = (W3@pos_w)[c][0], [128:160) PWx[c] = (W3@pos_w)[c][1], [160:192) pb3 = W3@pos_b
__global__ void compose_vecs(const float* __restrict__ bq, const float* __restrict__ bk,
                             const float* __restrict__ bv, const float* __restrict__ in_w,
                             const float* __restrict__ in_b, const float* __restrict__ pos_w,
                             const float* __restrict__ pos_b, float* __restrict__ V) {
    int tid = threadIdx.x;
    if (tid < 32) {
        float a = 0.f, b = 0.f, c = 0.f;
        #pragma unroll
        for (int t = 0; t < 32; ++t) {
            a += in_w[tid * 32 + t] * bq[t];
            b += in_w[(32 + tid) * 32 + t] * bk[t];
            c += in_w[(64 + tid) * 32 + t] * bv[t];
        }
        V[tid]      = a + in_b[tid];
        V[32 + tid] = b;
        V[64 + tid] = c;
    } else if (tid < 128) {
        int grp = (tid - 32) >> 5;   // 0=PWy 1=PWx 2=pb3
        int cp  = tid & 31;
        float acc = 0.f;
        #pragma unroll
        for (int t = 0; t < 32; ++t) {
            float src = (grp == 0) ? pos_w[t * 2 + 0] : ((grp == 1) ? pos_w[t * 2 + 1] : pos_b[t]);
            acc += in_w[(64 + cp) * 32 + t] * src;
        }
        V[96 + grp * 32 + cp] = acc;
    }
}

// ---------------- dense coord -> point-index grid ----------------
__global__ void build_grid(const int* __restrict__ coors, int* __restrict__ grid) {
    int P = blockIdx.x * blockDim.x + threadIdx.x;
    if (P >= NPTS) return;
    int b = P / NN;
    int n = P - b * NN;
    int y = coors[P * 2 + 0];
    int x = coors[P * 2 + 1];
    grid[b * HWPIX + y * WW + x] = n;
}

// ---------------- per-window occupied count ----------------
__global__ __launch_bounds__(256) void count_occ(const int* __restrict__ grid, int* __restrict__ cnt) {
    int tid = threadIdx.x;
    int pix = blockIdx.x * 256 + tid;
    bool occ = grid[pix] >= 0;
    unsigned long long mask = __ballot(occ);
    __shared__ int w[4];
    if ((tid & 63) == 0) w[tid >> 6] = __popcll(mask);
    __syncthreads();
    if (tid == 0) cnt[blockIdx.x] = w[0] + w[1] + w[2] + w[3];
}

// ---------------- exclusive scan of 2048 counts (single block) ----------------
__global__ __launch_bounds__(256) void scan2048(const int* __restrict__ cnt, int* __restrict__ off) {
    __shared__ int ps[256];
    int tid = threadIdx.x;
    int v[8], loc[8];
    int t = 0;
    #pragma unroll
    for (int k = 0; k < 8; ++k) { v[k] = cnt[tid * 8 + k]; loc[k] = t; t += v[k]; }
    ps[tid] = t;
    __syncthreads();
    for (int d = 1; d < 256; d <<= 1) {
        int val = ps[tid];
        int add = (tid >= d) ? ps[tid - d] : 0;
        __syncthreads();
        ps[tid] = val + add;
        __syncthreads();
    }
    int excl = (tid > 0) ? ps[tid - 1] : 0;
    #pragma unroll
    for (int k = 0; k < 8; ++k) off[tid * 8 + k] = excl + loc[k];
}

// ---------------- stage1: compact + LayerNorm + fused q/k/v linears ----------------
// Rewrites grid[pix] = global rank (in-place). Writes qp[rank], kv[rank] (rank-ordered).
__global__ __launch_bounds__(256) void stage1(const float* __restrict__ feats,
                                              const float* __restrict__ ln_w,
                                              const float* __restrict__ ln_b,
                                              const float* __restrict__ M,
                                              const float* __restrict__ V,
                                              const int* __restrict__ off,
                                              int* __restrict__ grid,
                                              float* __restrict__ qp,
                                              float* __restrict__ kv) {
    __shared__ float lw[3072];
    __shared__ int lsn[256], lsp[256];
    __shared__ int woff[4];

    int tid = threadIdx.x;
    int pix = blockIdx.x * 256 + tid;
    int n = grid[pix];
    bool occ = n >= 0;
    unsigned long long mask = __ballot(occ);
    int lane = tid & 63, wvi = tid >> 6;
    if (lane == 0) woff[wvi] = __popcll(mask);
    for (int i = tid; i < 3072; i += 256) lw[i] = M[i];
    __syncthreads();

    int pre = 0;
    for (int w = 0; w < wvi; ++w) pre += woff[w];
    int cnt = woff[0] + woff[1] + woff[2] + woff[3];
    int base = off[blockIdx.x];
    if (occ) {
        int slot = pre + __popcll(mask & ((1ull << lane) - 1ull));
        lsn[slot] = n;
        lsp[slot] = tid;
        grid[pix] = base + slot;
    }
    __syncthreads();

    int wid = tid >> 5, c = tid & 31;
    float lnw = ln_w[c], lnb = ln_b[c];
    float vq = V[c], vk = V[32 + c], vv = V[64 + c];
    int rounds = (cnt + 7) >> 3;
    for (int rd = 0; rd < rounds; ++rd) {
        int i = rd * 8 + wid;
        if (i < cnt) {
            int nn = lsn[i];
            int pixl = blockIdx.x * 256 + lsp[i];
            int b = pixl >> 18;
            float f = feats[((size_t)(b * NN + nn)) * 32 + c];
            float s1 = f, s2 = f * f;
            #pragma unroll
            for (int o2 = 16; o2 >= 1; o2 >>= 1) {
                s1 += __shfl_xor(s1, o2, 32);
                s2 += __shfl_xor(s2, o2, 32);
            }
            float mu  = s1 * (1.f / 32.f);
            float var = s2 * (1.f / 32.f) - mu * mu;
            float x = (f - mu) * rsqrtf(var + 1e-5f) * lnw + lnb;
            float aq = vq, ak = vk, av = vv;
            #pragma unroll
            for (int j = 0; j < 32; ++j) {
                float xv = __shfl(x, j, 32);
                aq += xv * lw[j * 32 + c];
                ak += xv * lw[1024 + j * 32 + c];
                av += xv * lw[2048 + j * 32 + c];
            }
            int r = base + i;
            qp[(size_t)r * 32 + c]      = aq;
            kv[(size_t)r * 64 + c]      = ak;
            kv[(size_t)r * 64 + 32 + c] = av;
        }
    }
}

// ---------------- stage2: per-(point,head) in-lane attention + fused out-proj ----------------
// Overwrites qp[rank] with the projected output row.
__global__ __launch_bounds__(256) void stage2(const int* __restrict__ grid,
                                              const float* __restrict__ kv,
                                              const float* __restrict__ M,
                                              const float* __restrict__ V,
                                              const float* __restrict__ in_b,
                                              const float* __restrict__ out_b,
                                              float* __restrict__ qp) {
    __shared__ int lsr[256], lsp[256];
    __shared__ int woff[4];
    __shared__ float lso[256 * 32];   // 32 KB

    int tid = threadIdx.x;
    int pix = blockIdx.x * 256 + tid;
    int rk = grid[pix];
    bool occ = rk >= 0;
    unsigned long long mask = __ballot(occ);
    int lane = tid & 63, wvi = tid >> 6;
    if (lane == 0) woff[wvi] = __popcll(mask);
    __syncthreads();
    int pre = 0;
    for (int w = 0; w < wvi; ++w) pre += woff[w];
    int cnt = woff[0] + woff[1] + woff[2] + woff[3];
    if (occ) {
        int slot = pre + __popcll(mask & ((1ull << lane) - 1ull));
        lsr[slot] = rk;
        lsp[slot] = tid;
    }
    __syncthreads();

    const int DYC[9] = {0,-1,1,0,-1,1,0,-1,1};
    const int DXC[9] = {0,0,0,1,1,1,-1,-1,-1};

    // ---- phase A: attention per (point, head) ----
    for (int task = tid; task < 2 * cnt; task += 256) {
        int i = task >> 1, h = task & 1;
        int r = lsr[i];
        int pixl = blockIdx.x * 256 + lsp[i];
        int b = pixl >> 18;
        int p = pixl & (HWPIX - 1);
        int y = p >> 9, x = p & 511;

        const float4* q4 = (const float4*)(qp + ((size_t)r << 5) + (h << 4));
        float4 qA = q4[0], qB = q4[1], qC = q4[2], qD = q4[3];
        const float4* ib2 = (const float4*)(in_b + 32 + (h << 4));
        float eb = dot4(qA, ib2[0]) + dot4(qB, ib2[1]) + dot4(qC, ib2[2]) + dot4(qD, ib2[3]);

        float lg[9];
        int nr[9];
        #pragma unroll
        for (int s = 0; s < 9; ++s) {
            int sy = y + DYC[s], sx = x + DXC[s];
            int t = -1;
            if (sy >= 0 && sy < HH && sx >= 0 && sx < WW)
                t = grid[(b << 18) + (sy << 9) + sx];
            nr[s] = t;
            float d = eb;
            if (t >= 0) {
                const float4* kp = (const float4*)(kv + ((size_t)t << 6) + (h << 4));
                float4 k0 = kp[0], k1 = kp[1], k2 = kp[2], k3 = kp[3];
                d += dot4(qA, k0) + dot4(qB, k1) + dot4(qC, k2) + dot4(qD, k3);
            }
            lg[s] = d * 0.25f;
        }
        float m = lg[0];
        #pragma unroll
        for (int s = 1; s < 9; ++s) m = fmaxf(m, lg[s]);
        float l = 0.f;
        #pragma unroll
        for (int s = 0; s < 9; ++s) { lg[s] = __expf(lg[s] - m); l += lg[s]; }

        float4 oA = {0,0,0,0}, oB = {0,0,0,0}, oC = {0,0,0,0}, oD = {0,0,0,0};
        float wdy = 0.f, wdx = 0.f, woc = 0.f;
        #pragma unroll
        for (int s = 0; s < 9; ++s) {
            if (nr[s] >= 0) {
                float w = lg[s];
                const float4* vp = (const float4*)(kv + ((size_t)nr[s] << 6) + 32 + (h << 4));
                float4 v0 = vp[0], v1 = vp[1], v2 = vp[2], v3 = vp[3];
                fma4(oA, w, v0); fma4(oB, w, v1); fma4(oC, w, v2); fma4(oD, w, v3);
                wdy += w * (float)DYC[s];
                wdx += w * (float)DXC[s];
                woc += w;
            }
        }
        float rl = 1.f / l;
        const float4* PY = (const float4*)(V + 96 + (h << 4));
        const float4* PX = (const float4*)(V + 128 + (h << 4));
        const float4* PB = (const float4*)(V + 160 + (h << 4));
        const float4* B3 = (const float4*)(in_b + 64 + (h << 4));
        float4* dst = (float4*)(lso + (i << 5) + (h << 4));
        dst[0] = fin4(oA, wdy, wdx, woc, rl, PY[0], PX[0], PB[0], B3[0]);
        dst[1] = fin4(oB, wdy, wdx, woc, rl, PY[1], PX[1], PB[1], B3[1]);
        dst[2] = fin4(oC, wdy, wdx, woc, rl, PY[2], PX[2], PB[2], B3[2]);
        dst[3] = fin4(oD, wdy, wdx, woc, rl, PY[3], PX[3], PB[3], B3[3]);
    }
    __syncthreads();

    // ---- phase B: out projection (32 lanes per point, weights per-lane in regs) ----
    int wid = tid >> 5, c = tid & 31;
    float ow[32];
    #pragma unroll
    for (int j = 0; j < 32; ++j) ow[j] = M[3072 + j * 32 + c];
    float ob = out_b[c];
    int rounds = (cnt + 7) >> 3;
    for (int rd = 0; rd < rounds; ++rd) {
        int i = rd * 8 + wid;
        if (i < cnt) {
            float acc = ob;
            #pragma unroll
            for (int j = 0; j < 32; ++j) acc += lso[(i << 5) + j] * ow[j];
            qp[((size_t)lsr[i] << 5) + c] = acc;
        }
    }
}

// ---------------- stage3: full-canvas write (rank reads are coalesced) ----------------
__global__ __launch_bounds__(256) void stage3(const int* __restrict__ grid,
                                              const float* __restrict__ obuf,
                                              float* __restrict__ out) {
    int t = blockIdx.x * blockDim.x + threadIdx.x;
    int b = t >> 18;
    int p = t & (HWPIX - 1);
    int rk = grid[t];
    float r[32];
    if (rk >= 0) {
        const float4* row = (const float4*)(obuf + ((size_t)rk << 5));
        #pragma unroll
        for (int i = 0; i < 8; ++i) ((float4*)r)[i] = row[i];
    } else {
        #pragma unroll
        for (int i = 0; i < 32; ++i) r[i] = 0.f;
    }
    float* outb = out + (size_t)b * CC * HWPIX + p;
    #pragma unroll
    for (int cc = 0; cc < 32; ++cc) outb[cc * HWPIX] = r[cc];
}

extern "C" void kernel_launch(void* const* d_in, const int* in_sizes, int n_in,
                              void* d_out, int out_size, void* d_ws, size_t ws_size,
                              hipStream_t stream) {
    const float* feats = (const float*)d_in[0];
    const int*   coors = (const int*)d_in[1];
    const float* ln_w  = (const float*)d_in[2];
    const float* ln_b  = (const float*)d_in[3];
    const float* wq    = (const float*)d_in[4];
    const float* bq    = (const float*)d_in[5];
    const float* wk    = (const float*)d_in[6];
    const float* bk    = (const float*)d_in[7];
    const float* wv    = (const float*)d_in[8];
    const float* bv    = (const float*)d_in[9];
    const float* pos_w = (const float*)d_in[10];
    const float* pos_b = (const float*)d_in[11];
    const float* in_w  = (const float*)d_in[12];
    const float* in_b  = (const float*)d_in[13];
    const float* out_w = (const float*)d_in[14];
    const float* out_b = (const float*)d_in[15];

    // workspace layout
    int*   grid = (int*)d_ws;                               // NPIX ints
    float* qp   = (float*)d_ws + NPIX;                      // NPTS*32 (reused as projected o)
    float* kv   = qp + (size_t)NPTS * 32;                   // NPTS*64 interleaved k|v
    float* M    = kv + (size_t)NPTS * 64;                   // 4096
    float* V    = M + 4096;                                 // 192
    size_t need = ((size_t)NPIX + (size_t)NPTS * 96 + 4096 + 192) * sizeof(float);
    if (ws_size < need) {
        fprintf(stderr, "kernel_launch: ws too small: %zu < %zu\n", ws_size, need);
        return;
    }
    // cnt/off scratch lives in the tail of d_out (stage3 rewrites all of d_out afterwards)
    int* cnt = (int*)d_out + (out_size - 4096);
    int* off = cnt + 2048;

    hipMemsetAsync(grid, 0xFF, (size_t)NPIX * sizeof(int), stream);   // grid = -1
    compose_mats<<<16, 256, 0, stream>>>(wq, wk, wv, in_w, out_w, M);
    compose_vecs<<<1, 128, 0, stream>>>(bq, bk, bv, in_w, in_b, pos_w, pos_b, V);
    build_grid<<<(NPTS + 255) / 256, 256, 0, stream>>>(coors, grid);
    count_occ<<<NBLK, 256, 0, stream>>>(grid, cnt);
    scan2048<<<1, 256, 0, stream>>>(cnt, off);
    stage1<<<NBLK, 256, 0, stream>>>(feats, ln_w, ln_b, M, V, off, grid, qp, kv);
    stage2<<<NBLK, 256, 0, stream>>>(grid, kv, M, V, in_b, out_b, qp);
    stage3<<<NBLK, 256, 0, stream>>>(grid, qp, (float*)d_out);
}

// Round 3
// 253.065 us; speedup vs baseline: 1.4961x; 1.2098x over previous
//
#include <hip/hip_runtime.h>
#include <cstdio>
#include <cstdint>

#define HH 512
#define WW 512
#define CC 32
#define BB 2
#define NN 120000
#define HWPIX (HH*WW)
#define NPTS (BB*NN)          // 240000
#define NPIX (BB*HWPIX)       // 524288
#define NBLK (NPIX/256)       // 2048

__device__ __forceinline__ float dot4(float4 a, float4 b) {
    return a.x*b.x + a.y*b.y + a.z*b.z + a.w*b.w;
}
__device__ __forceinline__ void fma4(float4& o, float w, float4 v) {
    o.x += w*v.x; o.y += w*v.y; o.z += w*v.z; o.w += w*v.w;
}
__device__ __forceinline__ float4 fin4(float4 o, float wdy, float wdx, float woc, float rl,
                                       float4 py, float4 px, float4 pb, float4 b3) {
    float4 r;
    r.x = (o.x + wdy*py.x + wdx*px.x + woc*pb.x)*rl + b3.x;
    r.y = (o.y + wdy*py.y + wdx*px.y + woc*pb.y)*rl + b3.y;
    r.z = (o.z + wdy*py.z + wdx*px.z + woc*pb.z)*rl + b3.z;
    r.w = (o.w + wdy*py.w + wdx*px.w + woc*pb.w)*rl + b3.w;
    return r;
}

// ---------------- compose fused weight matrices ----------------
// M layout (floats): [0:1024) MqT, [1024:2048) MkT, [2048:3072) MvT, [3072:4096) owT
// MxT[j*32+c'] = (W_proj @ w_x)[c'][j];  owT[j*32+c'] = out_w[c'][j]
__global__ void compose_mats(const float* __restrict__ wq, const float* __restrict__ wk,
                             const float* __restrict__ wv, const float* __restrict__ in_w,
                             const float* __restrict__ out_w, float* __restrict__ M) {
    int tid = blockIdx.x * blockDim.x + threadIdx.x;   // 0..4095
    if (tid >= 4096) return;
    int which = tid >> 10;
    int e = tid & 1023;
    int cp = e & 31;
    int j  = e >> 5;
    if (which < 3) {
        const float* w = (which == 0) ? wq : ((which == 1) ? wk : wv);
        const float* Wrow = in_w + (which * 32 + cp) * 32;
        float acc = 0.f;
        #pragma unroll
        for (int t = 0; t < 32; ++t) acc += Wrow[t] * w[t * 32 + j];
        M[which * 1024 + j * 32 + cp] = acc;
    } else {
        M[3 * 1024 + j * 32 + cp] = out_w[cp * 32 + j];
    }
}

// V layout (floats): [0:32) bq' = W1@bq + in_b[:32], [32:64) bk' = W2@bk, [64:96) bv' = W3@bv,
// [96:128) PWy[c] = (W3@pos_w)[c][0], [128:160) PWx[c] = (W3@pos_w)[c][1], [160:192) pb3 = W3@pos_b
__global__ void compose_vecs(const float* __restrict__ bq, const float* __restrict__ bk,
                             const float* __restrict__ bv, const float* __restrict__ in_w,
                             const float* __restrict__ in_b, const float* __restrict__ pos_w,
                             const float* __restrict__ pos_b, float* __restrict__ V) {
    int tid = threadIdx.x;
    if (tid < 32) {
        float a = 0.f, b = 0.f, c = 0.f;
        #pragma unroll
        for (int t = 0; t < 32; ++t) {
            a += in_w[tid * 32 + t] * bq[t];
            b += in_w[(32 + tid) * 32 + t] * bk[t];
            c += in_w[(64 + tid) * 32 + t] * bv[t];
        }
        V[tid]      = a + in_b[tid];
        V[32 + tid] = b;
        V[64 + tid] = c;
    } else if (tid < 128) {
        int grp = (tid - 32) >> 5;   // 0=PWy 1=PWx 2=pb3
        int cp  = tid & 31;
        float acc = 0.f;
        #pragma unroll
        for (int t = 0; t < 32; ++t) {
            float src = (grp == 0) ? pos_w[t * 2 + 0] : ((grp == 1) ? pos_w[t * 2 + 1] : pos_b[t]);
            acc += in_w[(64 + cp) * 32 + t] * src;
        }
        V[96 + grp * 32 + cp] = acc;
    }
}

// ---------------- dense coord -> point-index grid ----------------
__global__ void build_grid(const int* __restrict__ coors, int* __restrict__ grid) {
    int P = blockIdx.x * blockDim.x + threadIdx.x;
    if (P >= NPTS) return;
    int b = P / NN;
    int n = P - b * NN;
    int y = coors[P * 2 + 0];
    int x = coors[P * 2 + 1];
    grid[b * HWPIX + y * WW + x] = n;
}

// ---------------- per-window occupied count ----------------
__global__ __launch_bounds__(256) void count_occ(const int* __restrict__ grid, int* __restrict__ cnt) {
    int tid = threadIdx.x;
    int pix = blockIdx.x * 256 + tid;
    bool occ = grid[pix] >= 0;
    unsigned long long mask = __ballot(occ);
    __shared__ int w[4];
    if ((tid & 63) == 0) w[tid >> 6] = __popcll(mask);
    __syncthreads();
    if (tid == 0) cnt[blockIdx.x] = w[0] + w[1] + w[2] + w[3];
}

// ---------------- exclusive scan of 2048 counts (single block) ----------------
__global__ __launch_bounds__(256) void scan2048(const int* __restrict__ cnt, int* __restrict__ off) {
    __shared__ int ps[256];
    int tid = threadIdx.x;
    int v[8], loc[8];
    int t = 0;
    #pragma unroll
    for (int k = 0; k < 8; ++k) { v[k] = cnt[tid * 8 + k]; loc[k] = t; t += v[k]; }
    ps[tid] = t;
    __syncthreads();
    for (int d = 1; d < 256; d <<= 1) {
        int val = ps[tid];
        int add = (tid >= d) ? ps[tid - d] : 0;
        __syncthreads();
        ps[tid] = val + add;
        __syncthreads();
    }
    int excl = (tid > 0) ? ps[tid - 1] : 0;
    #pragma unroll
    for (int k = 0; k < 8; ++k) off[tid * 8 + k] = excl + loc[k];
}

// ---------------- stage1: compact + LayerNorm + fused q/k/v linears ----------------
// One thread per point; weights via uniform scalar loads (no LDS, no shuffles).
// Rewrites grid[pix] = global rank. Writes qp[rank], kv[rank] (rank-ordered).
__global__ __launch_bounds__(256) void stage1(const float* __restrict__ feats,
                                              const float* __restrict__ ln_w,
                                              const float* __restrict__ ln_b,
                                              const float* __restrict__ M,
                                              const float* __restrict__ V,
                                              const int* __restrict__ off,
                                              int* __restrict__ grid,
                                              float* __restrict__ qp,
                                              float* __restrict__ kv) {
    __shared__ int lsn[256];
    __shared__ int woff[4];

    int tid = threadIdx.x;
    int pix = blockIdx.x * 256 + tid;
    int n = grid[pix];
    bool occ = n >= 0;
    unsigned long long mask = __ballot(occ);
    int lane = tid & 63, wvi = tid >> 6;
    if (lane == 0) woff[wvi] = __popcll(mask);
    __syncthreads();
    int pre = 0;
    for (int w = 0; w < wvi; ++w) pre += woff[w];
    int cnt = woff[0] + woff[1] + woff[2] + woff[3];
    int base = off[blockIdx.x];
    if (occ) {
        int slot = pre + __popcll(mask & ((1ull << lane) - 1ull));
        lsn[slot] = n;
        grid[pix] = base + slot;
    }
    __syncthreads();

    if (cnt == 0) return;                      // uniform branch (keeps scalarization)
    bool active = tid < cnt;
    int i = active ? tid : 0;                  // clamp: safe loads for idle lanes
    int b = blockIdx.x >> 10;                  // 1024 blocks per batch image
    int nn = lsn[i];

    const float* fr = feats + ((size_t)(b * NN + nn) << 5);
    float x[32];
    #pragma unroll
    for (int k = 0; k < 8; ++k) ((float4*)x)[k] = ((const float4*)fr)[k];

    float s1 = 0.f, s2 = 0.f;
    #pragma unroll
    for (int j = 0; j < 32; ++j) { s1 += x[j]; s2 += x[j] * x[j]; }
    float mu   = s1 * (1.f / 32.f);
    float var  = s2 * (1.f / 32.f) - mu * mu;
    float rstd = rsqrtf(var + 1e-5f);
    #pragma unroll
    for (int j = 0; j < 32; ++j) x[j] = (x[j] - mu) * rstd * ln_w[j] + ln_b[j];

    int r = base + tid;
    float acc[32];

    // q' = x @ Mq + bq'
    #pragma unroll
    for (int c = 0; c < 32; ++c) acc[c] = V[c];
    #pragma unroll
    for (int j = 0; j < 32; ++j) {
        float xv = x[j];
        #pragma unroll
        for (int c = 0; c < 32; ++c) acc[c] += xv * M[j * 32 + c];
    }
    if (active) {
        float4* qd = (float4*)(qp + ((size_t)r << 5));
        #pragma unroll
        for (int k = 0; k < 8; ++k) qd[k] = ((float4*)acc)[k];
    }

    // k' = x @ Mk + bk'
    #pragma unroll
    for (int c = 0; c < 32; ++c) acc[c] = V[32 + c];
    #pragma unroll
    for (int j = 0; j < 32; ++j) {
        float xv = x[j];
        #pragma unroll
        for (int c = 0; c < 32; ++c) acc[c] += xv * M[1024 + j * 32 + c];
    }
    if (active) {
        float4* kd = (float4*)(kv + ((size_t)r << 6));
        #pragma unroll
        for (int k = 0; k < 8; ++k) kd[k] = ((float4*)acc)[k];
    }

    // v' = x @ Mv + bv'
    #pragma unroll
    for (int c = 0; c < 32; ++c) acc[c] = V[64 + c];
    #pragma unroll
    for (int j = 0; j < 32; ++j) {
        float xv = x[j];
        #pragma unroll
        for (int c = 0; c < 32; ++c) acc[c] += xv * M[2048 + j * 32 + c];
    }
    if (active) {
        float4* vd = (float4*)(kv + ((size_t)r << 6) + 32);
        #pragma unroll
        for (int k = 0; k < 8; ++k) vd[k] = ((float4*)acc)[k];
    }
}

// ---------------- stage2: per-(point,head) in-lane attention + fused out-proj ----------------
// Overwrites qp[rank] with the projected output row.
__global__ __launch_bounds__(256) void stage2(const int* __restrict__ grid,
                                              const float* __restrict__ kv,
                                              const float* __restrict__ M,
                                              const float* __restrict__ V,
                                              const float* __restrict__ in_b,
                                              const float* __restrict__ out_b,
                                              float* __restrict__ qp) {
    __shared__ int lsr[256], lsp[256];
    __shared__ int woff[4];
    __shared__ float lso[256 * 32];   // 32 KB

    int tid = threadIdx.x;
    int pix = blockIdx.x * 256 + tid;
    int rk = grid[pix];
    bool occ = rk >= 0;
    unsigned long long mask = __ballot(occ);
    int lane = tid & 63, wvi = tid >> 6;
    if (lane == 0) woff[wvi] = __popcll(mask);
    __syncthreads();
    int pre = 0;
    for (int w = 0; w < wvi; ++w) pre += woff[w];
    int cnt = woff[0] + woff[1] + woff[2] + woff[3];
    if (occ) {
        int slot = pre + __popcll(mask & ((1ull << lane) - 1ull));
        lsr[slot] = rk;
        lsp[slot] = tid;
    }
    __syncthreads();

    const int DYC[9] = {0,-1,1,0,-1,1,0,-1,1};
    const int DXC[9] = {0,0,0,1,1,1,-1,-1,-1};

    // ---- phase A: attention per (point, head) ----
    for (int task = tid; task < 2 * cnt; task += 256) {
        int i = task >> 1, h = task & 1;
        int r = lsr[i];
        int pixl = blockIdx.x * 256 + lsp[i];
        int b = pixl >> 18;
        int p = pixl & (HWPIX - 1);
        int y = p >> 9, x = p & 511;

        const float4* q4 = (const float4*)(qp + ((size_t)r << 5) + (h << 4));
        float4 qA = q4[0], qB = q4[1], qC = q4[2], qD = q4[3];
        const float4* ib2 = (const float4*)(in_b + 32 + (h << 4));
        float eb = dot4(qA, ib2[0]) + dot4(qB, ib2[1]) + dot4(qC, ib2[2]) + dot4(qD, ib2[3]);

        float lg[9];
        int nr[9];
        #pragma unroll
        for (int s = 0; s < 9; ++s) {
            int sy = y + DYC[s], sx = x + DXC[s];
            int t = -1;
            if (sy >= 0 && sy < HH && sx >= 0 && sx < WW)
                t = grid[(b << 18) + (sy << 9) + sx];
            nr[s] = t;
            float d = eb;
            if (t >= 0) {
                const float4* kp = (const float4*)(kv + ((size_t)t << 6) + (h << 4));
                float4 k0 = kp[0], k1 = kp[1], k2 = kp[2], k3 = kp[3];
                d += dot4(qA, k0) + dot4(qB, k1) + dot4(qC, k2) + dot4(qD, k3);
            }
            lg[s] = d * 0.25f;
        }
        float m = lg[0];
        #pragma unroll
        for (int s = 1; s < 9; ++s) m = fmaxf(m, lg[s]);
        float l = 0.f;
        #pragma unroll
        for (int s = 0; s < 9; ++s) { lg[s] = __expf(lg[s] - m); l += lg[s]; }

        float4 oA = {0,0,0,0}, oB = {0,0,0,0}, oC = {0,0,0,0}, oD = {0,0,0,0};
        float wdy = 0.f, wdx = 0.f, woc = 0.f;
        #pragma unroll
        for (int s = 0; s < 9; ++s) {
            if (nr[s] >= 0) {
                float w = lg[s];
                const float4* vp = (const float4*)(kv + ((size_t)nr[s] << 6) + 32 + (h << 4));
                float4 v0 = vp[0], v1 = vp[1], v2 = vp[2], v3 = vp[3];
                fma4(oA, w, v0); fma4(oB, w, v1); fma4(oC, w, v2); fma4(oD, w, v3);
                wdy += w * (float)DYC[s];
                wdx += w * (float)DXC[s];
                woc += w;
            }
        }
        float rl = 1.f / l;
        const float4* PY = (const float4*)(V + 96 + (h << 4));
        const float4* PX = (const float4*)(V + 128 + (h << 4));
        const float4* PB = (const float4*)(V + 160 + (h << 4));
        const float4* B3 = (const float4*)(in_b + 64 + (h << 4));
        float4* dst = (float4*)(lso + (i << 5) + (h << 4));
        dst[0] = fin4(oA, wdy, wdx, woc, rl, PY[0], PX[0], PB[0], B3[0]);
        dst[1] = fin4(oB, wdy, wdx, woc, rl, PY[1], PX[1], PB[1], B3[1]);
        dst[2] = fin4(oC, wdy, wdx, woc, rl, PY[2], PX[2], PB[2], B3[2]);
        dst[3] = fin4(oD, wdy, wdx, woc, rl, PY[3], PX[3], PB[3], B3[3]);
    }
    __syncthreads();

    // ---- phase B: out projection (32 lanes per point, weights per-lane in regs) ----
    int wid = tid >> 5, c = tid & 31;
    float ow[32];
    #pragma unroll
    for (int j = 0; j < 32; ++j) ow[j] = M[3072 + j * 32 + c];
    float ob = out_b[c];
    int rounds = (cnt + 7) >> 3;
    for (int rd = 0; rd < rounds; ++rd) {
        int i = rd * 8 + wid;
        if (i < cnt) {
            float acc = ob;
            #pragma unroll
            for (int j = 0; j < 32; ++j) acc += lso[(i << 5) + j] * ow[j];
            qp[((size_t)lsr[i] << 5) + c] = acc;
        }
    }
}

// ---------------- stage3: full-canvas write (rank reads are coalesced) ----------------
__global__ __launch_bounds__(256) void stage3(const int* __restrict__ grid,
                                              const float* __restrict__ obuf,
                                              float* __restrict__ out) {
    int t = blockIdx.x * blockDim.x + threadIdx.x;
    int b = t >> 18;
    int p = t & (HWPIX - 1);
    int rk = grid[t];
    float r[32];
    if (rk >= 0) {
        const float4* row = (const float4*)(obuf + ((size_t)rk << 5));
        #pragma unroll
        for (int i = 0; i < 8; ++i) ((float4*)r)[i] = row[i];
    } else {
        #pragma unroll
        for (int i = 0; i < 32; ++i) r[i] = 0.f;
    }
    float* outb = out + (size_t)b * CC * HWPIX + p;
    #pragma unroll
    for (int cc = 0; cc < 32; ++cc) outb[cc * HWPIX] = r[cc];
}

extern "C" void kernel_launch(void* const* d_in, const int* in_sizes, int n_in,
                              void* d_out, int out_size, void* d_ws, size_t ws_size,
                              hipStream_t stream) {
    const float* feats = (const float*)d_in[0];
    const int*   coors = (const int*)d_in[1];
    const float* ln_w  = (const float*)d_in[2];
    const float* ln_b  = (const float*)d_in[3];
    const float* wq    = (const float*)d_in[4];
    const float* bq    = (const float*)d_in[5];
    const float* wk    = (const float*)d_in[6];
    const float* bk    = (const float*)d_in[7];
    const float* wv    = (const float*)d_in[8];
    const float* bv    = (const float*)d_in[9];
    const float* pos_w = (const float*)d_in[10];
    const float* pos_b = (const float*)d_in[11];
    const float* in_w  = (const float*)d_in[12];
    const float* in_b  = (const float*)d_in[13];
    const float* out_w = (const float*)d_in[14];
    const float* out_b = (const float*)d_in[15];

    // workspace layout
    int*   grid = (int*)d_ws;                               // NPIX ints
    float* qp   = (float*)d_ws + NPIX;                      // NPTS*32 (reused as projected o)
    float* kv   = qp + (size_t)NPTS * 32;                   // NPTS*64 interleaved k|v
    float* M    = kv + (size_t)NPTS * 64;                   // 4096
    float* V    = M + 4096;                                 // 192
    size_t need = ((size_t)NPIX + (size_t)NPTS * 96 + 4096 + 192) * sizeof(float);
    if (ws_size < need) {
        fprintf(stderr, "kernel_launch: ws too small: %zu < %zu\n", ws_size, need);
        return;
    }
    // cnt/off scratch lives in the tail of d_out (stage3 rewrites all of d_out afterwards)
    int* cnt = (int*)d_out + (out_size - 4096);
    int* off = cnt + 2048;

    hipMemsetAsync(grid, 0xFF, (size_t)NPIX * sizeof(int), stream);   // grid = -1
    compose_mats<<<16, 256, 0, stream>>>(wq, wk, wv, in_w, out_w, M);
    compose_vecs<<<1, 128, 0, stream>>>(bq, bk, bv, in_w, in_b, pos_w, pos_b, V);
    build_grid<<<(NPTS + 255) / 256, 256, 0, stream>>>(coors, grid);
    count_occ<<<NBLK, 256, 0, stream>>>(grid, cnt);
    scan2048<<<1, 256, 0, stream>>>(cnt, off);
    stage1<<<NBLK, 256, 0, stream>>>(feats, ln_w, ln_b, M, V, off, grid, qp, kv);
    stage2<<<NBLK, 256, 0, stream>>>(grid, kv, M, V, in_b, out_b, qp);
    stage3<<<NBLK, 256, 0, stream>>>(grid, qp, (float*)d_out);
}